// Round 12
// baseline (6686.928 us; speedup 1.0000x reference)
//
#include <hip/hip_runtime.h>
#include <math.h>

// Problem constants (fixed by setup_inputs)
#define BB 64
#define CC 512
#define CR 32
#define HW 3136
#define HW4 784                    // HW/4 float4 per plane
#define GROUP_B 32                 // batches per L3-resident group (205.6 MB < 256 MB L3)
#define NGROUP (BB / GROUP_B)      // 2
#define PLANES_G (GROUP_B * CC)    // 16384 planes per group
#define WPB 4                      // waves per block (256 threads)
#define BLK_PER_BATCH 128          // 512 planes / 4 planes per block

typedef float f32x4 __attribute__((ext_vector_type(4)));

// ---------------------------------------------------------------------------
// Kernel 1: global average pool. One WAVE per plane; whole plane batched into
// registers (single vmcnt wait point). Normal loads populate L3 for scale.
// (identical to R10-206us)
// ---------------------------------------------------------------------------
__global__ __launch_bounds__(256) void se_pool(const float* __restrict__ x,
                                               float* __restrict__ s, int group) {
    const int wave = threadIdx.x >> 6;
    const int lane = threadIdx.x & 63;
    const int p = group * PLANES_G + blockIdx.x * WPB + wave;
    const f32x4* x4 = reinterpret_cast<const f32x4*>(x) + (size_t)p * HW4;

    f32x4 v[12];
    #pragma unroll
    for (int k = 0; k < 12; ++k)                   // 12 independent loads
        v[k] = x4[lane + 64 * k];
    f32x4 vt = (f32x4){0.f, 0.f, 0.f, 0.f};
    if (lane < 16) vt = x4[768 + lane];            // tail: 784 = 12*64 + 16

    #pragma unroll
    for (int k = 0; k < 6; ++k) v[k] += v[k + 6];
    #pragma unroll
    for (int k = 0; k < 3; ++k) v[k] += v[k + 3];
    f32x4 a = (v[0] + v[1]) + (v[2] + vt);
    float acc = (a.x + a.y) + (a.z + a.w);

    #pragma unroll
    for (int off = 32; off > 0; off >>= 1)
        acc += __shfl_down(acc, off, 64);
    if (lane == 0)
        s[p] = acc * (1.0f / (float)HW);
}

// ---------------------------------------------------------------------------
// Fallback: one wave computes its own gate for channel c of batch b directly
// from s (s is complete: the pool dispatch drained at the boundary). Rare —
// only taken if the fc-agent block is starved (co-residency not guaranteed).
// ---------------------------------------------------------------------------
__device__ float gate_fallback(const float* __restrict__ s,
                               const float* __restrict__ w1, const float* __restrict__ b1,
                               const float* __restrict__ w2, const float* __restrict__ b2,
                               int b, int c, int lane) {
    float ls[8];
    #pragma unroll
    for (int k = 0; k < 8; ++k)
        ls[k] = s[b * CC + lane + 64 * k];
    float gate = 0.0f;
    for (int r = 0; r < CR; ++r) {
        float pa = 0.0f;
        #pragma unroll
        for (int k = 0; k < 8; ++k)
            pa = fmaf(ls[k], w1[r * CC + lane + 64 * k], pa);
        #pragma unroll
        for (int off = 32; off > 0; off >>= 1)
            pa += __shfl_down(pa, off, 64);
        if (lane == 0) {
            float hr = fmaxf(pa + b1[r], 0.0f);
            gate = fmaf(hr, w2[c * CR + r], gate);
        }
    }
    if (lane == 0) gate = 1.0f / (1.0f + expf(-(gate + b2[c])));
    return __shfl(gate, 0, 64);
}

// ---------------------------------------------------------------------------
// Kernel 2: scale with embedded FC. One block per 4 planes (wave per plane).
// Block blk%128==0 is the fc AGENT for its batch: computes all 512 gates,
// publishes via agent-scope stores + release flag. Other blocks issue their
// x-loads first (in flight during the wait), then acquire the flag and
// agent-load their gate; bounded spin falls back to local computation.
// NT stores protect the L3 chunk (R11 evidence).
// ---------------------------------------------------------------------------
__global__ __launch_bounds__(256) void se_scale_fc(
    const float* __restrict__ x,
    const float* __restrict__ w1, const float* __restrict__ b1,
    const float* __restrict__ w2, const float* __restrict__ b2,
    const float* __restrict__ s, float* __restrict__ g,
    int* __restrict__ flag, float* __restrict__ out, int group)
{
    const int t    = threadIdx.x;
    const int wave = t >> 6;
    const int lane = t & 63;
    const int blk  = blockIdx.x;
    const int p    = group * PLANES_G + blk * WPB + wave;
    const int b    = p >> 9;                       // batch (CC == 512)
    const int c    = p & (CC - 1);

    // Issue this wave's plane loads immediately (in flight during fc wait).
    const size_t base = (size_t)p * HW4;
    const f32x4* x4 = reinterpret_cast<const f32x4*>(x) + base;
    f32x4*       o4 = reinterpret_cast<f32x4*>(out) + base;
    f32x4 v[12];
    #pragma unroll
    for (int k = 0; k < 12; ++k)
        v[k] = x4[lane + 64 * k];
    f32x4 vt;
    const bool tail = (lane < 16);                 // 784 = 12*64 + 16
    if (tail) vt = x4[768 + lane];

    float gv;
    if (blk % BLK_PER_BATCH == 0) {
        // ---- fc agent: compute all 512 gates for batch b ----
        __shared__ float s_sh[CC];
        __shared__ float h_sh[CR];
        s_sh[t]       = s[b * CC + t];
        s_sh[t + 256] = s[b * CC + t + 256];
        __syncthreads();
        {
            const int r = t >> 3, part = t & 7;
            const float* wr = w1 + r * CC;
            float ha = 0.0f;
            #pragma unroll
            for (int k = 0; k < CC / 8; ++k) {
                const int cc = part + 8 * k;
                ha = fmaf(s_sh[cc], wr[cc], ha);
            }
            ha += __shfl_down(ha, 4, 8);
            ha += __shfl_down(ha, 2, 8);
            ha += __shfl_down(ha, 1, 8);
            if (part == 0) h_sh[r] = fmaxf(ha + b1[r], 0.0f);
        }
        __syncthreads();
        float gmine = 0.0f;
        #pragma unroll
        for (int j = 0; j < 2; ++j) {
            const int c2 = t + j * 256;
            float a2 = b2[c2];
            const float* w2r = w2 + c2 * CR;
            #pragma unroll
            for (int rr = 0; rr < CR; ++rr)
                a2 = fmaf(h_sh[rr], w2r[rr], a2);
            a2 = 1.0f / (1.0f + expf(-a2));
            __hip_atomic_store(&g[b * CC + c2], a2,
                               __ATOMIC_RELAXED, __HIP_MEMORY_SCOPE_AGENT);
            if (c2 == c + (wave == 0 ? 0 : -1)) {} // (no-op; keep structure simple)
        }
        __syncthreads();
        if (t == 0)
            __hip_atomic_store(&flag[b], 1,
                               __ATOMIC_RELEASE, __HIP_MEMORY_SCOPE_AGENT);
        // agent re-load own gate (uniform path for all waves)
        gv = __hip_atomic_load(&g[p], __ATOMIC_RELAXED, __HIP_MEMORY_SCOPE_AGENT);
    } else {
        // ---- consumer: wait for the agent's flag; fallback if starved ----
        int ready = 0, spins = 0;
        while (!(ready = __hip_atomic_load(&flag[b], __ATOMIC_ACQUIRE,
                                           __HIP_MEMORY_SCOPE_AGENT)) &&
               spins < 4096) {
            ++spins;
            __builtin_amdgcn_s_sleep(1);
        }
        if (ready)
            gv = __hip_atomic_load(&g[p], __ATOMIC_RELAXED, __HIP_MEMORY_SCOPE_AGENT);
        else
            gv = gate_fallback(s, w1, b1, w2, b2, b, c, lane);
    }

    #pragma unroll
    for (int k = 0; k < 12; ++k)
        v[k] *= gv;
    if (tail) vt *= gv;

    #pragma unroll
    for (int k = 0; k < 12; ++k)
        __builtin_nontemporal_store(v[k], &o4[lane + 64 * k]);
    if (tail) __builtin_nontemporal_store(vt, &o4[768 + lane]);
}

// ---------------------------------------------------------------------------
extern "C" void kernel_launch(void* const* d_in, const int* in_sizes, int n_in,
                              void* d_out, int out_size, void* d_ws, size_t ws_size,
                              hipStream_t stream) {
    const float* x  = (const float*)d_in[0];
    const float* w1 = (const float*)d_in[1];
    const float* b1 = (const float*)d_in[2];
    const float* w2 = (const float*)d_in[3];
    const float* b2 = (const float*)d_in[4];
    float* out = (float*)d_out;

    float* s    = (float*)d_ws;                    // [BB*CC]
    float* g    = s + BB * CC;                     // [BB*CC]
    int*   flag = (int*)(g + BB * CC);             // [BB]

    // flags must be zero every call (replays don't re-poison ws)
    hipMemsetAsync(flag, 0, BB * sizeof(int), stream);

    for (int grp = 0; grp < NGROUP; ++grp) {
        se_pool    <<<PLANES_G / WPB, 256, 0, stream>>>(x, s, grp);
        se_scale_fc<<<PLANES_G / WPB, 256, 0, stream>>>(x, w1, b1, w2, b2,
                                                        s, g, flag, out, grp);
    }
}

// Round 13
// 377.012 us; speedup vs baseline: 17.7366x; 17.7366x over previous
//
#include <hip/hip_runtime.h>
#include <math.h>

// Problem constants (fixed by setup_inputs)
#define BB 64
#define CC 512
#define CR 32
#define HW 3136
#define HW4 784                     // HW/4 float4 per plane
#define NBLK 1024                   // 4 blocks/CU x 256 CU: ALL co-resident
#define BPB 128                     // blocks per batch (512 planes / 4 per block)
#define BATCH_PAR (NBLK / BPB)      // 8 batches in flight per round
#define ROUNDS (BB / BATCH_PAR)     // 8
#define POISON 0xFFFFFFFFu          // s[] init pattern; finite means never collide

typedef float f32x4 __attribute__((ext_vector_type(4)));

// ---------------------------------------------------------------------------
// Single persistent dispatch. Wave owns one plane per round (13 f32x4 = 52
// VGPR, safely under the 128 cap of launch_bounds(256,4) -> no spill, the R12
// killer). Round: pool plane into regs -> publish s[p] as a relaxed
// agent-scope word (word IS the flag: s[] is poison-initialized, so no
// fences, no barriers, no release/acquire L2 writeback storms [R2 lesson]) ->
// wave0 spin-reads the batch's s row -> tiny redundant fc per block -> scale
// the registers already in hand -> NT store. x crosses the fabric port ONCE.
// Deadlock-free: deps only among the 1024 co-resident blocks.
// ---------------------------------------------------------------------------
__global__ __launch_bounds__(256, 4) void se_onepass(
    const float* __restrict__ x,
    const float* __restrict__ w1, const float* __restrict__ b1,
    const float* __restrict__ w2, const float* __restrict__ b2,
    float* __restrict__ out, unsigned int* __restrict__ s)
{
    const int t    = threadIdx.x;
    const int wave = t >> 6;
    const int lane = t & 63;
    __shared__ float s_sh[CC];
    __shared__ float h_sh[CR];

    for (int r = 0; r < ROUNDS; ++r) {
        const int batch = r * BATCH_PAR + (int)blockIdx.x / BPB;
        const int jblk  = (int)blockIdx.x % BPB;
        const int c     = jblk * 4 + wave;        // this wave's channel
        const int p     = batch * CC + c;         // this wave's plane

        // ---- pool: whole plane into registers (one vmcnt wait point) ----
        const f32x4* x4 = reinterpret_cast<const f32x4*>(x) + (size_t)p * HW4;
        f32x4 v[12];
        #pragma unroll
        for (int k = 0; k < 12; ++k)
            v[k] = x4[lane + 64 * k];
        f32x4 vt = (f32x4){0.f, 0.f, 0.f, 0.f};
        const bool tail = (lane < 16);            // 784 = 12*64 + 16
        if (tail) vt = x4[768 + lane];

        f32x4 a = vt;
        #pragma unroll
        for (int k = 0; k < 6; ++k) a += (v[k] + v[k + 6]);
        float acc = (a.x + a.y) + (a.z + a.w);
        #pragma unroll
        for (int off = 32; off > 0; off >>= 1)
            acc += __shfl_down(acc, off, 64);
        if (lane == 0) {
            const float m = acc * (1.0f / (float)HW);
            __hip_atomic_store(&s[p], __float_as_uint(m),
                               __ATOMIC_RELAXED, __HIP_MEMORY_SCOPE_AGENT);
        }

        // ---- gather s row (wave 0 spins on poison words) ----
        __syncthreads();                          // prev-round LDS fully consumed
        if (wave == 0) {
            #pragma unroll
            for (int k = 0; k < 8; ++k) {
                const int idx = lane + 64 * k;
                unsigned int u;
                for (;;) {
                    u = __hip_atomic_load(&s[batch * CC + idx],
                                          __ATOMIC_RELAXED, __HIP_MEMORY_SCOPE_AGENT);
                    if (u != POISON) break;
                    __builtin_amdgcn_s_sleep(2);
                }
                s_sh[idx] = __uint_as_float(u);
            }
        }
        __syncthreads();                          // s_sh ready

        // ---- fc: h = relu(s @ w1^T + b1), 8 threads per row ----
        {
            const int row = t >> 3, part = t & 7;
            const float* wr = w1 + row * CC;
            float ha = 0.0f;
            #pragma unroll
            for (int k = 0; k < CC / 8; ++k) {
                const int cc2 = part + 8 * k;
                ha = fmaf(s_sh[cc2], wr[cc2], ha);
            }
            ha += __shfl_down(ha, 4, 8);
            ha += __shfl_down(ha, 2, 8);
            ha += __shfl_down(ha, 1, 8);
            if (part == 0) h_sh[row] = fmaxf(ha + b1[row], 0.0f);
        }
        __syncthreads();                          // h_sh ready

        // ---- gate (per-thread redundant 32-FMA dot) + scale + NT store ----
        float a2 = b2[c];
        const float* w2r = w2 + c * CR;
        #pragma unroll
        for (int rr = 0; rr < CR; ++rr)
            a2 = fmaf(h_sh[rr], w2r[rr], a2);
        const float gv = 1.0f / (1.0f + expf(-a2));

        f32x4* o4 = reinterpret_cast<f32x4*>(out) + (size_t)p * HW4;
        #pragma unroll
        for (int k = 0; k < 12; ++k)
            __builtin_nontemporal_store(v[k] * gv, &o4[lane + 64 * k]);
        if (tail) __builtin_nontemporal_store(vt * gv, &o4[768 + lane]);
    }
}

// ---------------------------------------------------------------------------
extern "C" void kernel_launch(void* const* d_in, const int* in_sizes, int n_in,
                              void* d_out, int out_size, void* d_ws, size_t ws_size,
                              hipStream_t stream) {
    const float* x  = (const float*)d_in[0];
    const float* w1 = (const float*)d_in[1];
    const float* b1 = (const float*)d_in[2];
    const float* w2 = (const float*)d_in[3];
    const float* b2 = (const float*)d_in[4];
    float* out = (float*)d_out;

    unsigned int* s = (unsigned int*)d_ws;        // [BB*CC] poison-init words

    // s must be poison at every call (replays don't re-poison ws)
    hipMemsetAsync(s, 0xFF, BB * CC * sizeof(unsigned int), stream);

    se_onepass<<<NBLK, 256, 0, stream>>>(x, w1, b1, w2, b2, out, s);
}